// Round 3
// baseline (906.632 us; speedup 1.0000x reference)
//
#include <hip/hip_runtime.h>
#include <math.h>

#define BATCH 4096
#define HDIM  1024
#define KDIM0 7150
#define KP0   7168
#define NACT  47
#define NA2   94
#define NEGC  -1000000000.0f

// output layout (floats): logits [0,385024), logp [385024,393216),
// actions [393216,401408), value [401408,405504)
#define LP_OFF  385024
#define ACT_OFF 393216
#define VAL_OFF 401408

typedef _Float16 half8_t  __attribute__((ext_vector_type(8)));
typedef _Float16 half4_t  __attribute__((ext_vector_type(4)));
typedef _Float16 half2_t  __attribute__((ext_vector_type(2)));
typedef float    float4_t __attribute__((ext_vector_type(4)));
typedef float    floatx16 __attribute__((ext_vector_type(16)));

// ---------------------------------------------------------------------------
// Weight convert: W[K][N] fp32 -> Wt_hi/Wt_lo f16 [N][Kp] (transposed, lo
// scaled by 4096; K zero-padded to Kp). 64x64 tiles via LDS.
// ---------------------------------------------------------------------------
__global__ __launch_bounds__(256) void wconv_kernel(
    const float* __restrict__ W, _Float16* __restrict__ Wh,
    _Float16* __restrict__ Wl, int K, int N, int Kp)
{
  __shared__ float T[64][65];
  const int k0 = blockIdx.x * 64, n0 = blockIdx.y * 64, t = threadIdx.x;
#pragma unroll
  for (int p = 0; p < 16; ++p) {
    const int idx = p * 256 + t;
    const int r = idx >> 6, c = idx & 63;
    T[r][c] = (k0 + r < K) ? W[(size_t)(k0 + r) * N + n0 + c] : 0.f;
  }
  __syncthreads();
  const int n = t >> 2, kc = (t & 3) * 16;
#pragma unroll
  for (int e = 0; e < 16; ++e) {
    const float v = T[kc + e][n];
    const _Float16 h = (_Float16)v;
    const float r = v - (float)h;
    const _Float16 l = (_Float16)(r * 4096.f);
    const size_t o = (size_t)(n0 + n) * Kp + k0 + kc + e;
    Wh[o] = h; Wl[o] = l;
  }
}

// ---------------------------------------------------------------------------
// f16x3 split GEMM, 32x32x16 MFMA, block tile 128x128, BK=64, split-K with
// fp32 atomicAdd epilogue. A given as f16 hi/lo planes [M][Kp], W as
// transposed hi/lo planes [N][Kp].  4 waves 2x2; wave tile 64x64 = 2x2 MFMA
// tiles. acc = hi*hi ; accx = hi*lo + lo*hi (lo scaled 2^12).
// LDS XOR-swizzled at 16B -> conflict-free frag reads (verified R2: 0 cnf).
// ---------------------------------------------------------------------------
__global__ __launch_bounds__(256, 2) void gemm_f16x3_kernel(
    const _Float16* __restrict__ Ah, const _Float16* __restrict__ Al,
    const _Float16* __restrict__ Wh, const _Float16* __restrict__ Wl,
    float* __restrict__ C, int Kp, int N, int ksplit)
{
  __shared__ __align__(16) _Float16 As[2][128 * 64];
  __shared__ __align__(16) _Float16 Ws[2][128 * 64];
  const int t = threadIdx.x;
  const int n0 = blockIdx.x * 128;
  const int m0 = blockIdx.y * 128;
  const int kbeg = blockIdx.z * ksplit;
  const int kend = kbeg + ksplit;
  const int lane = t & 63;
  const int wid = t >> 6;
  const int wm = (wid >> 1) * 64;
  const int wn = (wid & 1) * 64;
  const int l31 = lane & 31;
  const int kh  = lane >> 5;          // 0/1 : k-half of the fragment

  const int sp = t >> 7;              // staging plane 0/1
  const int sr = (t & 127) >> 3;      // staging row within 16
  const int sc = t & 7;               // staging 16B chunk
  const _Float16* Ap = sp ? Al : Ah;
  const _Float16* Wp = sp ? Wl : Wh;

  floatx16 acc[2][2], accx[2][2];
#pragma unroll
  for (int i = 0; i < 2; ++i)
#pragma unroll
    for (int j = 0; j < 2; ++j) {
      acc[i][j] = (floatx16)(0.f);
      accx[i][j] = (floatx16)(0.f);
    }

  for (int k0 = kbeg; k0 < kend; k0 += 64) {
#pragma unroll
    for (int q = 0; q < 8; ++q) {
      const int m = q * 16 + sr;
      const float4_t v = *(const float4_t*)(Ap + (size_t)(m0 + m) * Kp + k0 + sc * 8);
      *(float4_t*)&As[sp][m * 64 + ((sc ^ (m & 7)) << 3)] = v;
    }
#pragma unroll
    for (int q = 0; q < 8; ++q) {
      const int n = q * 16 + sr;
      const float4_t v = *(const float4_t*)(Wp + (size_t)(n0 + n) * Kp + k0 + sc * 8);
      *(float4_t*)&Ws[sp][n * 64 + ((sc ^ (n & 7)) << 3)] = v;
    }
    __syncthreads();
#pragma unroll
    for (int ks = 0; ks < 4; ++ks) {
      half8_t ah[2], al[2], wh[2], wl[2];
      const int cch = ks * 2 + kh;
#pragma unroll
      for (int i = 0; i < 2; ++i) {
        const int row = wm + i * 32 + l31;
        const int o = row * 64 + ((cch ^ (row & 7)) << 3);
        ah[i] = *(const half8_t*)&As[0][o];
        al[i] = *(const half8_t*)&As[1][o];
      }
#pragma unroll
      for (int j = 0; j < 2; ++j) {
        const int col = wn + j * 32 + l31;
        const int o = col * 64 + ((cch ^ (col & 7)) << 3);
        wh[j] = *(const half8_t*)&Ws[0][o];
        wl[j] = *(const half8_t*)&Ws[1][o];
      }
#pragma unroll
      for (int i = 0; i < 2; ++i)
#pragma unroll
        for (int j = 0; j < 2; ++j) {
          acc[i][j]  = __builtin_amdgcn_mfma_f32_32x32x16_f16(ah[i], wh[j], acc[i][j], 0, 0, 0);
          accx[i][j] = __builtin_amdgcn_mfma_f32_32x32x16_f16(ah[i], wl[j], accx[i][j], 0, 0, 0);
          accx[i][j] = __builtin_amdgcn_mfma_f32_32x32x16_f16(al[i], wh[j], accx[i][j], 0, 0, 0);
        }
    }
    __syncthreads();
  }
  const float s = 1.0f / 4096.0f;
#pragma unroll
  for (int i = 0; i < 2; ++i)
#pragma unroll
    for (int j = 0; j < 2; ++j) {
      const int col = n0 + wn + j * 32 + l31;
#pragma unroll
      for (int r = 0; r < 16; ++r) {
        const int row = m0 + wm + i * 32 + (r & 3) + 8 * (r >> 2) + 4 * kh;
        atomicAdd(C + (size_t)row * N + col, acc[i][j][r] + accx[i][j][r] * s);
      }
    }
}

// ---------------------------------------------------------------------------
// Same GEMM, but A is fp32 [M][K] decomposed in-kernel during staging
// (layer 0: fuses the obs hi/lo split; K guarded on last chunk only).
// ---------------------------------------------------------------------------
__global__ __launch_bounds__(256, 2) void gemm_f16x3_a32_kernel(
    const float* __restrict__ A,
    const _Float16* __restrict__ Wh, const _Float16* __restrict__ Wl,
    float* __restrict__ C, int K, int N, int ksplit)
{
  __shared__ __align__(16) _Float16 As[2][128 * 64];
  __shared__ __align__(16) _Float16 Ws[2][128 * 64];
  const int t = threadIdx.x;
  const int n0 = blockIdx.x * 128;
  const int m0 = blockIdx.y * 128;
  const int kbeg = blockIdx.z * ksplit;
  const int kend = kbeg + ksplit;
  const int lane = t & 63;
  const int wid = t >> 6;
  const int wm = (wid >> 1) * 64;
  const int wn = (wid & 1) * 64;
  const int l31 = lane & 31;
  const int kh  = lane >> 5;

  const int sp = t >> 7;
  const int sr = (t & 127) >> 3;
  const int sc = t & 7;
  const _Float16* Wp = sp ? Wl : Wh;

  const int a_k2 = (t & 31) * 2;      // k offset (float2 granularity)
  const int a_mr = t >> 5;            // row within 8

  floatx16 acc[2][2], accx[2][2];
#pragma unroll
  for (int i = 0; i < 2; ++i)
#pragma unroll
    for (int j = 0; j < 2; ++j) {
      acc[i][j] = (floatx16)(0.f);
      accx[i][j] = (floatx16)(0.f);
    }

  for (int k0 = kbeg; k0 < kend; k0 += 64) {
    if (k0 + 64 <= K) {
#pragma unroll
      for (int q = 0; q < 16; ++q) {
        const int m = q * 8 + a_mr;
        const float2 v = *(const float2*)(A + (size_t)(m0 + m) * K + k0 + a_k2);
        const _Float16 h0 = (_Float16)v.x; const float r0 = v.x - (float)h0;
        const _Float16 h1 = (_Float16)v.y; const float r1 = v.y - (float)h1;
        const int o = m * 64 + (((a_k2 >> 3) ^ (m & 7)) << 3) + (a_k2 & 7);
        *(half2_t*)&As[0][o] = (half2_t){h0, h1};
        *(half2_t*)&As[1][o] = (half2_t){(_Float16)(r0 * 4096.f), (_Float16)(r1 * 4096.f)};
      }
    } else {
#pragma unroll
      for (int q = 0; q < 16; ++q) {
        const int m = q * 8 + a_mr;
        const float x0 = (k0 + a_k2     < K) ? A[(size_t)(m0 + m) * K + k0 + a_k2]     : 0.f;
        const float x1 = (k0 + a_k2 + 1 < K) ? A[(size_t)(m0 + m) * K + k0 + a_k2 + 1] : 0.f;
        const _Float16 h0 = (_Float16)x0; const float r0 = x0 - (float)h0;
        const _Float16 h1 = (_Float16)x1; const float r1 = x1 - (float)h1;
        const int o = m * 64 + (((a_k2 >> 3) ^ (m & 7)) << 3) + (a_k2 & 7);
        *(half2_t*)&As[0][o] = (half2_t){h0, h1};
        *(half2_t*)&As[1][o] = (half2_t){(_Float16)(r0 * 4096.f), (_Float16)(r1 * 4096.f)};
      }
    }
#pragma unroll
    for (int q = 0; q < 8; ++q) {
      const int n = q * 16 + sr;
      const float4_t v = *(const float4_t*)(Wp + (size_t)(n0 + n) * KP0 + k0 + sc * 8);
      *(float4_t*)&Ws[sp][n * 64 + ((sc ^ (n & 7)) << 3)] = v;
    }
    __syncthreads();
#pragma unroll
    for (int ks = 0; ks < 4; ++ks) {
      half8_t ah[2], al[2], wh[2], wl[2];
      const int cch = ks * 2 + kh;
#pragma unroll
      for (int i = 0; i < 2; ++i) {
        const int row = wm + i * 32 + l31;
        const int o = row * 64 + ((cch ^ (row & 7)) << 3);
        ah[i] = *(const half8_t*)&As[0][o];
        al[i] = *(const half8_t*)&As[1][o];
      }
#pragma unroll
      for (int j = 0; j < 2; ++j) {
        const int col = wn + j * 32 + l31;
        const int o = col * 64 + ((cch ^ (col & 7)) << 3);
        wh[j] = *(const half8_t*)&Ws[0][o];
        wl[j] = *(const half8_t*)&Ws[1][o];
      }
#pragma unroll
      for (int i = 0; i < 2; ++i)
#pragma unroll
        for (int j = 0; j < 2; ++j) {
          acc[i][j]  = __builtin_amdgcn_mfma_f32_32x32x16_f16(ah[i], wh[j], acc[i][j], 0, 0, 0);
          accx[i][j] = __builtin_amdgcn_mfma_f32_32x32x16_f16(ah[i], wl[j], accx[i][j], 0, 0, 0);
          accx[i][j] = __builtin_amdgcn_mfma_f32_32x32x16_f16(al[i], wh[j], accx[i][j], 0, 0, 0);
        }
    }
    __syncthreads();
  }
  const float s = 1.0f / 4096.0f;
#pragma unroll
  for (int i = 0; i < 2; ++i)
#pragma unroll
    for (int j = 0; j < 2; ++j) {
      const int col = n0 + wn + j * 32 + l31;
#pragma unroll
      for (int r = 0; r < 16; ++r) {
        const int row = m0 + wm + i * 32 + (r & 3) + 8 * (r >> 2) + 4 * kh;
        atomicAdd(C + (size_t)row * N + col, acc[i][j][r] + accx[i][j][r] * s);
      }
    }
}

// ---------------------------------------------------------------------------
// bias + LayerNorm + ReLU, output as f16 hi/lo planes (next GEMM's A input)
// ---------------------------------------------------------------------------
__global__ __launch_bounds__(256) void ln_relu_f16_kernel(
    const float* __restrict__ x, const float* __restrict__ bias,
    const float* __restrict__ g, const float* __restrict__ be,
    _Float16* __restrict__ oh, _Float16* __restrict__ ol)
{
  __shared__ float red[8];
  const int b = blockIdx.x, t = threadIdx.x;
  const float* row = x + (size_t)b * HDIM;
  float4 v = *(const float4*)(row + t * 4);
  const float4 bb = *(const float4*)(bias + t * 4);
  v.x += bb.x; v.y += bb.y; v.z += bb.z; v.w += bb.w;

  float s = (v.x + v.y) + (v.z + v.w);
#pragma unroll
  for (int o = 32; o; o >>= 1) s += __shfl_xor(s, o, 64);
  const int wid = t >> 6, lane = t & 63;
  if (lane == 0) red[wid] = s;
  __syncthreads();
  const float mean = (red[0] + red[1] + red[2] + red[3]) * (1.0f / HDIM);

  const float dx = v.x - mean, dy = v.y - mean, dz = v.z - mean, dw = v.w - mean;
  float s2 = (dx * dx + dy * dy) + (dz * dz + dw * dw);
#pragma unroll
  for (int o = 32; o; o >>= 1) s2 += __shfl_xor(s2, o, 64);
  if (lane == 0) red[4 + wid] = s2;
  __syncthreads();
  const float var = (red[4] + red[5] + red[6] + red[7]) * (1.0f / HDIM);
  const float inv = 1.0f / sqrtf(var + 1e-5f);

  const float4 gg = *(const float4*)(g + t * 4);
  const float4 ee = *(const float4*)(be + t * 4);
  float r0 = fmaxf(fmaf(dx * inv, gg.x, ee.x), 0.f);
  float r1 = fmaxf(fmaf(dy * inv, gg.y, ee.y), 0.f);
  float r2 = fmaxf(fmaf(dz * inv, gg.z, ee.z), 0.f);
  float r3 = fmaxf(fmaf(dw * inv, gg.w, ee.w), 0.f);
  const _Float16 h0 = (_Float16)r0, h1 = (_Float16)r1, h2 = (_Float16)r2, h3 = (_Float16)r3;
  const half4_t hv = {h0, h1, h2, h3};
  const half4_t lv = {(_Float16)((r0 - (float)h0) * 4096.f),
                      (_Float16)((r1 - (float)h1) * 4096.f),
                      (_Float16)((r2 - (float)h2) * 4096.f),
                      (_Float16)((r3 - (float)h3) * 4096.f)};
  *(half4_t*)(oh + (size_t)b * HDIM + t * 4) = hv;
  *(half4_t*)(ol + (size_t)b * HDIM + t * 4) = lv;
}

// ---------------------------------------------------------------------------
// bias + LayerNorm + ReLU in-place fp32 (final layer; head reads fp32)
// ---------------------------------------------------------------------------
__global__ __launch_bounds__(256) void ln_relu_kernel(
    float* __restrict__ x, const float* __restrict__ bias,
    const float* __restrict__ g, const float* __restrict__ be)
{
  __shared__ float red[8];
  const int b = blockIdx.x, t = threadIdx.x;
  float* row = x + (size_t)b * HDIM;
  float4 v = *(float4*)(row + t * 4);
  const float4 bb = *(const float4*)(bias + t * 4);
  v.x += bb.x; v.y += bb.y; v.z += bb.z; v.w += bb.w;

  float s = (v.x + v.y) + (v.z + v.w);
#pragma unroll
  for (int o = 32; o; o >>= 1) s += __shfl_xor(s, o, 64);
  const int wid = t >> 6, lane = t & 63;
  if (lane == 0) red[wid] = s;
  __syncthreads();
  const float mean = (red[0] + red[1] + red[2] + red[3]) * (1.0f / HDIM);

  const float dx = v.x - mean, dy = v.y - mean, dz = v.z - mean, dw = v.w - mean;
  float s2 = (dx * dx + dy * dy) + (dz * dz + dw * dw);
#pragma unroll
  for (int o = 32; o; o >>= 1) s2 += __shfl_xor(s2, o, 64);
  if (lane == 0) red[4 + wid] = s2;
  __syncthreads();
  const float var = (red[4] + red[5] + red[6] + red[7]) * (1.0f / HDIM);
  const float inv = 1.0f / sqrtf(var + 1e-5f);

  const float4 gg = *(const float4*)(g + t * 4);
  const float4 ee = *(const float4*)(be + t * 4);
  float4 r;
  r.x = fmaxf(fmaf(dx * inv, gg.x, ee.x), 0.f);
  r.y = fmaxf(fmaf(dy * inv, gg.y, ee.y), 0.f);
  r.z = fmaxf(fmaf(dz * inv, gg.z, ee.z), 0.f);
  r.w = fmaxf(fmaf(dw * inv, gg.w, ee.w), 0.f);
  *(float4*)(row + t * 4) = r;
}

// ---------------------------------------------------------------------------
// Pack Wcat[1024][96]: cols 0..93 = Wp, col 94 = Wv, col 95 = 0
// ---------------------------------------------------------------------------
__global__ __launch_bounds__(256) void pack_wcat_kernel(
    const float* __restrict__ Wp, const float* __restrict__ Wv,
    float* __restrict__ Wc)
{
  const int i = blockIdx.x * 256 + threadIdx.x;
  const int k = i / 96, c = i % 96;
  float v = 0.f;
  if (c < 94)       v = Wp[(size_t)k * 94 + c];
  else if (c == 94) v = Wv[k];
  Wc[i] = v;
}

// ---------------------------------------------------------------------------
// Head: out[r, 0..93] = x@Wp + bp, value[r] = x@Wv + bv. fp32 VALU.
// ---------------------------------------------------------------------------
__global__ __launch_bounds__(256) void head_kernel(
    const float* __restrict__ X, const float* __restrict__ Wc,
    const float* __restrict__ bp, const float* __restrict__ bv,
    float* __restrict__ out)
{
  __shared__ float Xs[8][1025];
  __shared__ float red[4][8][96];
  const int t  = threadIdx.x;
  const int r0 = blockIdx.x * 8;
  const int tx = t & 15;
  const int ty = (t >> 4) & 3;
  const int kz = t >> 6;
  const int c0 = tx * 6;

#pragma unroll 4
  for (int i = 0; i < 32; ++i) {
    const int e = i * 256 + t;
    Xs[e >> 10][e & 1023] = X[(size_t)(r0 + (e >> 10)) * HDIM + (e & 1023)];
  }
  __syncthreads();

  float acc[2][6] = {{0.f,0.f,0.f,0.f,0.f,0.f},{0.f,0.f,0.f,0.f,0.f,0.f}};
  const int kkend = kz * 256 + 256;
  for (int kk = kz * 256; kk < kkend; ++kk) {
    const float x0 = Xs[ty * 2][kk];
    const float x1 = Xs[ty * 2 + 1][kk];
    const float* wrow = Wc + (size_t)kk * 96 + c0;
    const float2 w01 = *(const float2*)(wrow);
    const float2 w23 = *(const float2*)(wrow + 2);
    const float2 w45 = *(const float2*)(wrow + 4);
    const float wv[6] = {w01.x, w01.y, w23.x, w23.y, w45.x, w45.y};
#pragma unroll
    for (int j = 0; j < 6; ++j) {
      acc[0][j] = fmaf(x0, wv[j], acc[0][j]);
      acc[1][j] = fmaf(x1, wv[j], acc[1][j]);
    }
  }
#pragma unroll
  for (int r = 0; r < 2; ++r)
#pragma unroll
    for (int j = 0; j < 6; ++j) red[kz][ty * 2 + r][c0 + j] = acc[r][j];
  __syncthreads();

#pragma unroll
  for (int q = 0; q < 3; ++q) {
    const int e = t * 3 + q;
    const int row = e / 96, c = e % 96;
    const float sum = red[0][row][c] + red[1][row][c] + red[2][row][c] + red[3][row][c];
    if (c < 94)       out[(size_t)(r0 + row) * NA2 + c] = sum + bp[c];
    else if (c == 94) out[VAL_OFF + r0 + row] = sum + bv[0];
  }
}

// ---------------------------------------------------------------------------
// Sampling: one wave per batch row.
// ---------------------------------------------------------------------------
__global__ __launch_bounds__(64) void sample_kernel(
    const int* __restrict__ amask, const float* __restrict__ gum,
    float* __restrict__ out)
{
  const int b = blockIdx.x, lane = threadIdx.x;
  const bool valid = lane < NACT;
  const float* lrow = out + (size_t)b * NA2;

  const float lg1 = valid ? lrow[lane] : 0.f;
  const float lg2 = valid ? lrow[NACT + lane] : 0.f;
  const int   mk1 = valid ? amask[(size_t)b * NA2 + lane] : 0;
  const int   mk2 = valid ? amask[(size_t)b * NA2 + NACT + lane] : 0;
  const float gu1 = valid ? gum[(size_t)b * NA2 + lane] : 0.f;
  const float gu2 = valid ? gum[(size_t)b * NA2 + NACT + lane] : 0.f;

  const float l1 = valid ? ((mk1 == 0) ? NEGC : lg1) : -INFINITY;
  float key = valid ? (l1 + gu1) : -INFINITY;
  int idx = lane;
#pragma unroll
  for (int o = 32; o; o >>= 1) {
    const float ok = __shfl_xor(key, o, 64);
    const int   oi = __shfl_xor(idx, o, 64);
    if (ok > key || (ok == key && oi < idx)) { key = ok; idx = oi; }
  }
  const int a1 = idx;

  float mx = l1;
#pragma unroll
  for (int o = 32; o; o >>= 1) mx = fmaxf(mx, __shfl_xor(mx, o, 64));
  float ex = valid ? expf(l1 - mx) : 0.f;
#pragma unroll
  for (int o = 32; o; o >>= 1) ex += __shfl_xor(ex, o, 64);
  const float logp1 = __shfl(l1, a1, 64) - (mx + logf(ex));

  int m2 = mk2;
  if (a1 >= 1 && a1 <= 6 && lane == a1) m2 = 0;
  if (a1 > 26 && a1 <= 46 && lane >= 27 && valid) m2 = 0;
  if (a1 == 0 && lane == 0) m2 = 0;
  int tot = m2;
#pragma unroll
  for (int o = 32; o; o >>= 1) tot += __shfl_xor(tot, o, 64);
  if (a1 == 0 && tot == 0 && lane == 0) m2 = 1;

  const float l2 = valid ? ((m2 == 0) ? NEGC : lg2) : -INFINITY;
  float key2 = valid ? (l2 + gu2) : -INFINITY;
  int idx2 = lane;
#pragma unroll
  for (int o = 32; o; o >>= 1) {
    const float ok = __shfl_xor(key2, o, 64);
    const int   oi = __shfl_xor(idx2, o, 64);
    if (ok > key2 || (ok == key2 && oi < idx2)) { key2 = ok; idx2 = oi; }
  }
  const int a2 = idx2;

  float mx2 = l2;
#pragma unroll
  for (int o = 32; o; o >>= 1) mx2 = fmaxf(mx2, __shfl_xor(mx2, o, 64));
  float ex2 = valid ? expf(l2 - mx2) : 0.f;
#pragma unroll
  for (int o = 32; o; o >>= 1) ex2 += __shfl_xor(ex2, o, 64);
  const float logp2 = __shfl(l2, a2, 64) - (mx2 + logf(ex2));

  if (lane == 0) {
    out[LP_OFF  + b * 2]     = logp1;
    out[LP_OFF  + b * 2 + 1] = logp2;
    out[ACT_OFF + b * 2]     = (float)a1;
    out[ACT_OFF + b * 2 + 1] = (float)a2;
  }
}

// ---------------------------------------------------------------------------
extern "C" void kernel_launch(void* const* d_in, const int* in_sizes, int n_in,
                              void* d_out, int out_size, void* d_ws, size_t ws_size,
                              hipStream_t stream) {
  (void)in_sizes; (void)n_in; (void)out_size; (void)ws_size;
  const float* obs   = (const float*)d_in[0];
  const int*   amask = (const int*)  d_in[1];
  const float* gum   = (const float*)d_in[2];
  const float* W0    = (const float*)d_in[3];
  const float* b0    = (const float*)d_in[4];
  const float* g0    = (const float*)d_in[5];
  const float* be0   = (const float*)d_in[6];
  const float* W1    = (const float*)d_in[7];
  const float* b1    = (const float*)d_in[8];
  const float* g1    = (const float*)d_in[9];
  const float* be1   = (const float*)d_in[10];
  const float* W2    = (const float*)d_in[11];
  const float* b2    = (const float*)d_in[12];
  const float* g2    = (const float*)d_in[13];
  const float* be2   = (const float*)d_in[14];
  const float* Wp    = (const float*)d_in[15];
  const float* bp    = (const float*)d_in[16];
  const float* Wv    = (const float*)d_in[17];
  const float* bv    = (const float*)d_in[18];
  float* out = (float*)d_out;

  char* ws = (char*)d_ws;
  size_t off = 0;
  auto take = [&](size_t n) { char* p = ws + off; off += (n + 255) & ~(size_t)255; return p; };
  _Float16* wt0h = (_Float16*)take((size_t)HDIM * KP0 * 2);
  _Float16* wt0l = (_Float16*)take((size_t)HDIM * KP0 * 2);
  _Float16* wt1h = (_Float16*)take((size_t)HDIM * HDIM * 2);
  _Float16* wt1l = (_Float16*)take((size_t)HDIM * HDIM * 2);
  _Float16* wt2h = (_Float16*)take((size_t)HDIM * HDIM * 2);
  _Float16* wt2l = (_Float16*)take((size_t)HDIM * HDIM * 2);
  float*    xf   = (float*)   take((size_t)BATCH * HDIM * 4);
  float*    wc   = (float*)   take((size_t)HDIM * 96 * 4);
  _Float16* xph  = (_Float16*)take((size_t)BATCH * HDIM * 2);
  _Float16* xpl  = (_Float16*)take((size_t)BATCH * HDIM * 2);
  const size_t xbytes = (size_t)BATCH * HDIM * sizeof(float);

  // weight conversions (transpose + f16 hi/lo decompose)
  wconv_kernel<<<dim3(KP0 / 64, HDIM / 64), 256, 0, stream>>>(W0, wt0h, wt0l, KDIM0, HDIM, KP0);
  wconv_kernel<<<dim3(16, 16), 256, 0, stream>>>(W1, wt1h, wt1l, HDIM, HDIM, HDIM);
  wconv_kernel<<<dim3(16, 16), 256, 0, stream>>>(W2, wt2h, wt2l, HDIM, HDIM, HDIM);
  pack_wcat_kernel<<<384, 256, 0, stream>>>(Wp, Wv, wc);

  // layer 0: fused obs decompose + split-K(2) MFMA GEMM
  hipMemsetAsync(xf, 0, xbytes, stream);
  gemm_f16x3_a32_kernel<<<dim3(8, 32, 2), 256, 0, stream>>>(
      obs, wt0h, wt0l, xf, KDIM0, HDIM, KP0 / 2);
  ln_relu_f16_kernel<<<BATCH, 256, 0, stream>>>(xf, b0, g0, be0, xph, xpl);

  // layer 1
  hipMemsetAsync(xf, 0, xbytes, stream);
  gemm_f16x3_kernel<<<dim3(8, 32, 2), 256, 0, stream>>>(
      xph, xpl, wt1h, wt1l, xf, HDIM, HDIM, HDIM / 2);
  ln_relu_f16_kernel<<<BATCH, 256, 0, stream>>>(xf, b1, g1, be1, xph, xpl);

  // layer 2
  hipMemsetAsync(xf, 0, xbytes, stream);
  gemm_f16x3_kernel<<<dim3(8, 32, 2), 256, 0, stream>>>(
      xph, xpl, wt2h, wt2l, xf, HDIM, HDIM, HDIM / 2);
  ln_relu_kernel<<<BATCH, 256, 0, stream>>>(xf, b2, g2, be2);

  // heads + sampling
  head_kernel<<<BATCH / 8, 256, 0, stream>>>(xf, wc, bp, bv, out);
  sample_kernel<<<BATCH, 64, 0, stream>>>(amask, gum, out);
}

// Round 4
// 686.337 us; speedup vs baseline: 1.3210x; 1.3210x over previous
//
#include <hip/hip_runtime.h>
#include <math.h>

#define BATCH 4096
#define HDIM  1024
#define KDIM0 7150
#define KP0   7168
#define KT0   224          // KP0/32
#define KTH   32           // HDIM/32
#define NACT  47
#define NA2   94
#define NEGC  -1000000000.0f

// output layout (floats): logits [0,385024), logp [385024,393216),
// actions [393216,401408), value [401408,405504)
#define LP_OFF  385024
#define ACT_OFF 393216
#define VAL_OFF 401408

typedef _Float16 half8_t  __attribute__((ext_vector_type(8)));
typedef _Float16 half4_t  __attribute__((ext_vector_type(4)));
typedef float    float4_t __attribute__((ext_vector_type(4)));

// async global->LDS, 16B per lane: global addr = per-lane, LDS = wave-uniform base
#define GLOAD16(gp, lp) __builtin_amdgcn_global_load_lds( \
    (__attribute__((address_space(1))) void*)(gp), \
    (__attribute__((address_space(3))) void*)(lp), 16, 0, 0)

// Fragment-tile order for a [R][Kp] f16 plane (R = rows of A, or cols of W^T):
//   tile = rt*KT + kt   (rt = r/16, kt = k/32)
//   within tile: lane = quad*16 + (r%16), quad = (k%32)/8, j = k%8
//   halfs addr = tile*512 + lane*8 + j
// This is exactly the mfma_f32_16x16x32_f16 A/B lane layout (verified on-HW in R2).

// ---------------------------------------------------------------------------
// Weight convert: W[K][HDIM] fp32 -> hi/lo f16 planes of W^T in fragment order.
// ---------------------------------------------------------------------------
__global__ __launch_bounds__(256) void wconv_frag_kernel(
    const float* __restrict__ W, _Float16* __restrict__ Wh,
    _Float16* __restrict__ Wl, int K, int KT)
{
  __shared__ float T[64][65];
  const int k0 = blockIdx.x * 64, n0 = blockIdx.y * 64, t = threadIdx.x;
#pragma unroll
  for (int p = 0; p < 16; ++p) {
    const int idx = p * 256 + t;
    const int r = idx >> 6, c = idx & 63;
    T[r][c] = (k0 + r < K) ? W[(size_t)(k0 + r) * HDIM + n0 + c] : 0.f;
  }
  __syncthreads();
#pragma unroll
  for (int ss = 0; ss < 2; ++ss) {
    const int s    = ss * 256 + t;
    const int tile = s >> 6;            // 0..7 = 2 kt x 4 nt
    const int ktl  = tile >> 2, ntl = tile & 3;
    const int lane = s & 63;
    const int quad = lane >> 4, nr = lane & 15;
    half8_t h, l;
#pragma unroll
    for (int j = 0; j < 8; ++j) {
      const float v = T[ktl * 32 + quad * 8 + j][ntl * 16 + nr];
      const _Float16 hh = (_Float16)v;
      h[j] = hh;
      l[j] = (_Float16)((v - (float)hh) * 4096.f);
    }
    const size_t o = ((size_t)((n0 / 16 + ntl) * KT + (k0 / 32 + ktl)) * 64 + lane) * 8;
    *(half8_t*)(Wh + o) = h;
    *(half8_t*)(Wl + o) = l;
  }
}

// ---------------------------------------------------------------------------
// obs decompose: obs[4096][7150] fp32 -> hi/lo planes [4096][7168] frag order.
// Block: 16 rows x 256 k, LDS bounce for read/write coalescing.
// ---------------------------------------------------------------------------
__global__ __launch_bounds__(256) void adecomp_frag_kernel(
    const float* __restrict__ A, _Float16* __restrict__ Ah,
    _Float16* __restrict__ Al)
{
  __shared__ float Xs[16][257];
  const int t  = threadIdx.x;
  const int mt = blockIdx.y;
  const int kb = blockIdx.x * 256;
  const int lr = t >> 4;              // load row 0..15
  const int lk = (t & 15) * 16;       // load k offset within 256
  const float* src = A + (size_t)(mt * 16 + lr) * KDIM0 + kb + lk;
#pragma unroll
  for (int c = 0; c < 4; ++c) {
    const int kg = kb + lk + c * 4;
    float4 vv = make_float4(0.f, 0.f, 0.f, 0.f);
    if (kg + 3 < KDIM0) {
      vv = *(const float4*)(src + c * 4);
    } else {
      if (kg     < KDIM0) vv.x = src[c * 4];
      if (kg + 1 < KDIM0) vv.y = src[c * 4 + 1];
      if (kg + 2 < KDIM0) vv.z = src[c * 4 + 2];
      if (kg + 3 < KDIM0) vv.w = src[c * 4 + 3];
    }
    *(float4*)&Xs[lr][lk + c * 4] = vv;
  }
  __syncthreads();
#pragma unroll
  for (int ss = 0; ss < 2; ++ss) {
    const int s    = ss * 256 + t;
    const int ktl  = s >> 6;            // 0..7
    const int lane = s & 63;
    const int quad = lane >> 4, mr = lane & 15;
    half8_t h, l;
#pragma unroll
    for (int j = 0; j < 8; ++j) {
      const float v = Xs[mr][ktl * 32 + quad * 8 + j];
      const _Float16 hh = (_Float16)v;
      h[j] = hh;
      l[j] = (_Float16)((v - (float)hh) * 4096.f);
    }
    const size_t o = ((size_t)(mt * KT0 + blockIdx.x * 8 + ktl) * 64 + lane) * 8;
    *(half8_t*)(Ah + o) = h;
    *(half8_t*)(Al + o) = l;
  }
}

// ---------------------------------------------------------------------------
// f16x3 split GEMM, 16x16x32 MFMA, fragment-order inputs, global_load_lds
// staging. Block 128x128, 512 thr = 8 waves (2m x 4n), wave tile 64x32.
// BK = 32 (one k-tile per stage). Split-K, fp32 atomicAdd epilogue.
// ---------------------------------------------------------------------------
__global__ __launch_bounds__(512, 4) void gemm_frag_kernel(
    const _Float16* __restrict__ Ah, const _Float16* __restrict__ Al,
    const _Float16* __restrict__ Wh, const _Float16* __restrict__ Wl,
    float* __restrict__ C, int KT, int ktsplit)
{
  __shared__ _Float16 As[2][8][512];
  __shared__ _Float16 Ws[2][8][512];
  const int t    = threadIdx.x;
  const int lane = t & 63;
  const int w    = t >> 6;
  const int nt0  = blockIdx.x * 8;
  const int mt0  = blockIdx.y * 8;
  const int ktb  = blockIdx.z * ktsplit;
  const int kte  = ktb + ktsplit;
  const int l15  = lane & 15, quad = lane >> 4;
  const int wmi  = (w >> 2) * 4;      // wave m-tile base (tiles)
  const int wni  = (w & 3) * 2;       // wave n-tile base (tiles)

  // staging assignment: tile s = w*4+q; s<16 -> A (plane s>>3, mt s&7),
  // s>=16 -> W (plane, nt). One global_load_lds per tile per k-step.
  const _Float16* gsrc[4];
  _Float16*       ldst[4];
#pragma unroll
  for (int q = 0; q < 4; ++q) {
    const int s = w * 4 + q;
    const _Float16* plane;
    int rowt;
    _Float16* d;
    if (s < 16) {
      plane = (s & 8) ? Al : Ah;
      rowt  = mt0 + (s & 7);
      d     = &As[s >> 3][s & 7][0];
    } else {
      const int s2 = s - 16;
      plane = (s2 & 8) ? Wl : Wh;
      rowt  = nt0 + (s2 & 7);
      d     = &Ws[s2 >> 3][s2 & 7][0];
    }
    gsrc[q] = plane + (size_t)rowt * KT * 512 + lane * 8;
    ldst[q] = d;
  }

  float4_t acc[4][2], accx[4][2];
#pragma unroll
  for (int i = 0; i < 4; ++i)
#pragma unroll
    for (int j = 0; j < 2; ++j) {
      acc[i][j]  = (float4_t){0.f, 0.f, 0.f, 0.f};
      accx[i][j] = (float4_t){0.f, 0.f, 0.f, 0.f};
    }

  for (int kt = ktb; kt < kte; ++kt) {
#pragma unroll
    for (int q = 0; q < 4; ++q)
      GLOAD16(gsrc[q] + (size_t)kt * 512, ldst[q]);
    __syncthreads();

    half8_t ah[4], al[4], wh[2], wl[2];
#pragma unroll
    for (int i = 0; i < 4; ++i) {
      ah[i] = *(const half8_t*)&As[0][wmi + i][lane * 8];
      al[i] = *(const half8_t*)&As[1][wmi + i][lane * 8];
    }
#pragma unroll
    for (int j = 0; j < 2; ++j) {
      wh[j] = *(const half8_t*)&Ws[0][wni + j][lane * 8];
      wl[j] = *(const half8_t*)&Ws[1][wni + j][lane * 8];
    }
#pragma unroll
    for (int i = 0; i < 4; ++i)
#pragma unroll
      for (int j = 0; j < 2; ++j) {
        acc[i][j]  = __builtin_amdgcn_mfma_f32_16x16x32_f16(ah[i], wh[j], acc[i][j], 0, 0, 0);
        accx[i][j] = __builtin_amdgcn_mfma_f32_16x16x32_f16(ah[i], wl[j], accx[i][j], 0, 0, 0);
        accx[i][j] = __builtin_amdgcn_mfma_f32_16x16x32_f16(al[i], wh[j], accx[i][j], 0, 0, 0);
      }
    __syncthreads();
  }

  const float sc = 1.0f / 4096.0f;
#pragma unroll
  for (int i = 0; i < 4; ++i) {
    const int row0 = (mt0 + wmi + i) * 16 + quad * 4;
#pragma unroll
    for (int j = 0; j < 2; ++j) {
      const int col = (nt0 + wni + j) * 16 + l15;
      float* cp = C + (size_t)row0 * HDIM + col;
#pragma unroll
      for (int r = 0; r < 4; ++r)
        atomicAdd(cp + (size_t)r * HDIM, acc[i][j][r] + accx[i][j][r] * sc);
    }
  }
}

// ---------------------------------------------------------------------------
// bias + LayerNorm + ReLU -> hi/lo f16 planes in fragment order.
// Block = 1024 thr = 16 waves; wave w handles row mt*16+w (wave-local reduce).
// ---------------------------------------------------------------------------
__global__ __launch_bounds__(1024) void ln_relu_f16_frag_kernel(
    const float* __restrict__ x, const float* __restrict__ bias,
    const float* __restrict__ g, const float* __restrict__ be,
    _Float16* __restrict__ oh, _Float16* __restrict__ ol)
{
  const int t = threadIdx.x;
  const int w = t >> 6, lane = t & 63;
  const int mt = blockIdx.x;
  const float* xr = x + (size_t)(mt * 16 + w) * HDIM;

  float4 v[4];
  float s = 0.f;
#pragma unroll
  for (int c = 0; c < 4; ++c) {
    const int k = c * 256 + lane * 4;
    v[c] = *(const float4*)(xr + k);
    const float4 bb = *(const float4*)(bias + k);
    v[c].x += bb.x; v[c].y += bb.y; v[c].z += bb.z; v[c].w += bb.w;
    s += (v[c].x + v[c].y) + (v[c].z + v[c].w);
  }
#pragma unroll
  for (int o = 32; o; o >>= 1) s += __shfl_xor(s, o, 64);
  const float mean = s * (1.0f / HDIM);

  float s2 = 0.f;
#pragma unroll
  for (int c = 0; c < 4; ++c) {
    v[c].x -= mean; v[c].y -= mean; v[c].z -= mean; v[c].w -= mean;
    s2 += (v[c].x * v[c].x + v[c].y * v[c].y) + (v[c].z * v[c].z + v[c].w * v[c].w);
  }
#pragma unroll
  for (int o = 32; o; o >>= 1) s2 += __shfl_xor(s2, o, 64);
  const float inv = 1.0f / sqrtf(s2 * (1.0f / HDIM) + 1e-5f);

  const int kt_b  = lane >> 3;          // 0..7 (added to c*8)
  const int quad  = (lane >> 1) & 3;
  const int jb    = (lane & 1) * 4;
#pragma unroll
  for (int c = 0; c < 4; ++c) {
    const int k = c * 256 + lane * 4;
    const float4 gg = *(const float4*)(g + k);
    const float4 ee = *(const float4*)(be + k);
    float r0 = fmaxf(fmaf(v[c].x * inv, gg.x, ee.x), 0.f);
    float r1 = fmaxf(fmaf(v[c].y * inv, gg.y, ee.y), 0.f);
    float r2 = fmaxf(fmaf(v[c].z * inv, gg.z, ee.z), 0.f);
    float r3 = fmaxf(fmaf(v[c].w * inv, gg.w, ee.w), 0.f);
    const _Float16 h0 = (_Float16)r0, h1 = (_Float16)r1, h2 = (_Float16)r2, h3 = (_Float16)r3;
    const half4_t hv = {h0, h1, h2, h3};
    const half4_t lv = {(_Float16)((r0 - (float)h0) * 4096.f),
                        (_Float16)((r1 - (float)h1) * 4096.f),
                        (_Float16)((r2 - (float)h2) * 4096.f),
                        (_Float16)((r3 - (float)h3) * 4096.f)};
    const int kt = c * 8 + kt_b;
    const size_t o = ((size_t)(mt * KTH + kt) * 64 + quad * 16 + w) * 8 + jb;
    *(half4_t*)(oh + o) = hv;
    *(half4_t*)(ol + o) = lv;
  }
}

// ---------------------------------------------------------------------------
// bias + LayerNorm + ReLU in-place fp32 (final layer; head reads fp32)
// ---------------------------------------------------------------------------
__global__ __launch_bounds__(256) void ln_relu_kernel(
    float* __restrict__ x, const float* __restrict__ bias,
    const float* __restrict__ g, const float* __restrict__ be)
{
  __shared__ float red[8];
  const int b = blockIdx.x, t = threadIdx.x;
  float* row = x + (size_t)b * HDIM;
  float4 v = *(float4*)(row + t * 4);
  const float4 bb = *(const float4*)(bias + t * 4);
  v.x += bb.x; v.y += bb.y; v.z += bb.z; v.w += bb.w;

  float s = (v.x + v.y) + (v.z + v.w);
#pragma unroll
  for (int o = 32; o; o >>= 1) s += __shfl_xor(s, o, 64);
  const int wid = t >> 6, lane = t & 63;
  if (lane == 0) red[wid] = s;
  __syncthreads();
  const float mean = (red[0] + red[1] + red[2] + red[3]) * (1.0f / HDIM);

  const float dx = v.x - mean, dy = v.y - mean, dz = v.z - mean, dw = v.w - mean;
  float s2 = (dx * dx + dy * dy) + (dz * dz + dw * dw);
#pragma unroll
  for (int o = 32; o; o >>= 1) s2 += __shfl_xor(s2, o, 64);
  if (lane == 0) red[4 + wid] = s2;
  __syncthreads();
  const float var = (red[4] + red[5] + red[6] + red[7]) * (1.0f / HDIM);
  const float inv = 1.0f / sqrtf(var + 1e-5f);

  const float4 gg = *(const float4*)(g + t * 4);
  const float4 ee = *(const float4*)(be + t * 4);
  float4 r;
  r.x = fmaxf(fmaf(dx * inv, gg.x, ee.x), 0.f);
  r.y = fmaxf(fmaf(dy * inv, gg.y, ee.y), 0.f);
  r.z = fmaxf(fmaf(dz * inv, gg.z, ee.z), 0.f);
  r.w = fmaxf(fmaf(dw * inv, gg.w, ee.w), 0.f);
  *(float4*)(row + t * 4) = r;
}

// ---------------------------------------------------------------------------
// Pack Wcat[1024][96]: cols 0..93 = Wp, col 94 = Wv, col 95 = 0
// ---------------------------------------------------------------------------
__global__ __launch_bounds__(256) void pack_wcat_kernel(
    const float* __restrict__ Wp, const float* __restrict__ Wv,
    float* __restrict__ Wc)
{
  const int i = blockIdx.x * 256 + threadIdx.x;
  const int k = i / 96, c = i % 96;
  float v = 0.f;
  if (c < 94)       v = Wp[(size_t)k * 94 + c];
  else if (c == 94) v = Wv[k];
  Wc[i] = v;
}

// ---------------------------------------------------------------------------
// Head: out[r, 0..93] = x@Wp + bp, value[r] = x@Wv + bv. fp32 VALU.
// ---------------------------------------------------------------------------
__global__ __launch_bounds__(256) void head_kernel(
    const float* __restrict__ X, const float* __restrict__ Wc,
    const float* __restrict__ bp, const float* __restrict__ bv,
    float* __restrict__ out)
{
  __shared__ float Xs[8][1025];
  __shared__ float red[4][8][96];
  const int t  = threadIdx.x;
  const int r0 = blockIdx.x * 8;
  const int tx = t & 15;
  const int ty = (t >> 4) & 3;
  const int kz = t >> 6;
  const int c0 = tx * 6;

#pragma unroll 4
  for (int i = 0; i < 32; ++i) {
    const int e = i * 256 + t;
    Xs[e >> 10][e & 1023] = X[(size_t)(r0 + (e >> 10)) * HDIM + (e & 1023)];
  }
  __syncthreads();

  float acc[2][6] = {{0.f,0.f,0.f,0.f,0.f,0.f},{0.f,0.f,0.f,0.f,0.f,0.f}};
  const int kkend = kz * 256 + 256;
  for (int kk = kz * 256; kk < kkend; ++kk) {
    const float x0 = Xs[ty * 2][kk];
    const float x1 = Xs[ty * 2 + 1][kk];
    const float* wrow = Wc + (size_t)kk * 96 + c0;
    const float2 w01 = *(const float2*)(wrow);
    const float2 w23 = *(const float2*)(wrow + 2);
    const float2 w45 = *(const float2*)(wrow + 4);
    const float wv[6] = {w01.x, w01.y, w23.x, w23.y, w45.x, w45.y};
#pragma unroll
    for (int j = 0; j < 6; ++j) {
      acc[0][j] = fmaf(x0, wv[j], acc[0][j]);
      acc[1][j] = fmaf(x1, wv[j], acc[1][j]);
    }
  }
#pragma unroll
  for (int r = 0; r < 2; ++r)
#pragma unroll
    for (int j = 0; j < 6; ++j) red[kz][ty * 2 + r][c0 + j] = acc[r][j];
  __syncthreads();

#pragma unroll
  for (int q = 0; q < 3; ++q) {
    const int e = t * 3 + q;
    const int row = e / 96, c = e % 96;
    const float sum = red[0][row][c] + red[1][row][c] + red[2][row][c] + red[3][row][c];
    if (c < 94)       out[(size_t)(r0 + row) * NA2 + c] = sum + bp[c];
    else if (c == 94) out[VAL_OFF + r0 + row] = sum + bv[0];
  }
}

// ---------------------------------------------------------------------------
// Sampling: one wave per batch row.
// ---------------------------------------------------------------------------
__global__ __launch_bounds__(64) void sample_kernel(
    const int* __restrict__ amask, const float* __restrict__ gum,
    float* __restrict__ out)
{
  const int b = blockIdx.x, lane = threadIdx.x;
  const bool valid = lane < NACT;
  const float* lrow = out + (size_t)b * NA2;

  const float lg1 = valid ? lrow[lane] : 0.f;
  const float lg2 = valid ? lrow[NACT + lane] : 0.f;
  const int   mk1 = valid ? amask[(size_t)b * NA2 + lane] : 0;
  const int   mk2 = valid ? amask[(size_t)b * NA2 + NACT + lane] : 0;
  const float gu1 = valid ? gum[(size_t)b * NA2 + lane] : 0.f;
  const float gu2 = valid ? gum[(size_t)b * NA2 + NACT + lane] : 0.f;

  const float l1 = valid ? ((mk1 == 0) ? NEGC : lg1) : -INFINITY;
  float key = valid ? (l1 + gu1) : -INFINITY;
  int idx = lane;
#pragma unroll
  for (int o = 32; o; o >>= 1) {
    const float ok = __shfl_xor(key, o, 64);
    const int   oi = __shfl_xor(idx, o, 64);
    if (ok > key || (ok == key && oi < idx)) { key = ok; idx = oi; }
  }
  const int a1 = idx;

  float mx = l1;
#pragma unroll
  for (int o = 32; o; o >>= 1) mx = fmaxf(mx, __shfl_xor(mx, o, 64));
  float ex = valid ? expf(l1 - mx) : 0.f;
#pragma unroll
  for (int o = 32; o; o >>= 1) ex += __shfl_xor(ex, o, 64);
  const float logp1 = __shfl(l1, a1, 64) - (mx + logf(ex));

  int m2 = mk2;
  if (a1 >= 1 && a1 <= 6 && lane == a1) m2 = 0;
  if (a1 > 26 && a1 <= 46 && lane >= 27 && valid) m2 = 0;
  if (a1 == 0 && lane == 0) m2 = 0;
  int tot = m2;
#pragma unroll
  for (int o = 32; o; o >>= 1) tot += __shfl_xor(tot, o, 64);
  if (a1 == 0 && tot == 0 && lane == 0) m2 = 1;

  const float l2 = valid ? ((m2 == 0) ? NEGC : lg2) : -INFINITY;
  float key2 = valid ? (l2 + gu2) : -INFINITY;
  int idx2 = lane;
#pragma unroll
  for (int o = 32; o; o >>= 1) {
    const float ok = __shfl_xor(key2, o, 64);
    const int   oi = __shfl_xor(idx2, o, 64);
    if (ok > key2 || (ok == key2 && oi < idx2)) { key2 = ok; idx2 = oi; }
  }
  const int a2 = idx2;

  float mx2 = l2;
#pragma unroll
  for (int o = 32; o; o >>= 1) mx2 = fmaxf(mx2, __shfl_xor(mx2, o, 64));
  float ex2 = valid ? expf(l2 - mx2) : 0.f;
#pragma unroll
  for (int o = 32; o; o >>= 1) ex2 += __shfl_xor(ex2, o, 64);
  const float logp2 = __shfl(l2, a2, 64) - (mx2 + logf(ex2));

  if (lane == 0) {
    out[LP_OFF  + b * 2]     = logp1;
    out[LP_OFF  + b * 2 + 1] = logp2;
    out[ACT_OFF + b * 2]     = (float)a1;
    out[ACT_OFF + b * 2 + 1] = (float)a2;
  }
}

// ---------------------------------------------------------------------------
extern "C" void kernel_launch(void* const* d_in, const int* in_sizes, int n_in,
                              void* d_out, int out_size, void* d_ws, size_t ws_size,
                              hipStream_t stream) {
  (void)in_sizes; (void)n_in; (void)out_size; (void)ws_size;
  const float* obs   = (const float*)d_in[0];
  const int*   amask = (const int*)  d_in[1];
  const float* gum   = (const float*)d_in[2];
  const float* W0    = (const float*)d_in[3];
  const float* b0    = (const float*)d_in[4];
  const float* g0    = (const float*)d_in[5];
  const float* be0   = (const float*)d_in[6];
  const float* W1    = (const float*)d_in[7];
  const float* b1    = (const float*)d_in[8];
  const float* g1    = (const float*)d_in[9];
  const float* be1   = (const float*)d_in[10];
  const float* W2    = (const float*)d_in[11];
  const float* b2    = (const float*)d_in[12];
  const float* g2    = (const float*)d_in[13];
  const float* be2   = (const float*)d_in[14];
  const float* Wp    = (const float*)d_in[15];
  const float* bp    = (const float*)d_in[16];
  const float* Wv    = (const float*)d_in[17];
  const float* bv    = (const float*)d_in[18];
  float* out = (float*)d_out;

  char* ws = (char*)d_ws;
  size_t off = 0;
  auto take = [&](size_t n) { char* p = ws + off; off += (n + 255) & ~(size_t)255; return p; };
  _Float16* obsh = (_Float16*)take((size_t)BATCH * KP0 * 2);   // 58.7 MB
  _Float16* obsl = (_Float16*)take((size_t)BATCH * KP0 * 2);   // 58.7 MB
  _Float16* w0h  = (_Float16*)take((size_t)HDIM * KP0 * 2);    // 14.7 MB
  _Float16* w0l  = (_Float16*)take((size_t)HDIM * KP0 * 2);    // 14.7 MB
  _Float16* w1h  = (_Float16*)take((size_t)HDIM * HDIM * 2);
  _Float16* w1l  = (_Float16*)take((size_t)HDIM * HDIM * 2);
  _Float16* w2h  = (_Float16*)take((size_t)HDIM * HDIM * 2);
  _Float16* w2l  = (_Float16*)take((size_t)HDIM * HDIM * 2);
  float*    xf   = (float*)   take((size_t)BATCH * HDIM * 4);  // 16.8 MB
  float*    wc   = (float*)   take((size_t)HDIM * 96 * 4);
  // activation f16 planes alias the (dead after GEMM0) W0 plane region
  _Float16* xph  = w0h;   // 8.4 MB needed, 14.7 available
  _Float16* xpl  = w0l;
  const size_t xbytes = (size_t)BATCH * HDIM * sizeof(float);

  // conversions into fragment order
  wconv_frag_kernel<<<dim3(KP0 / 64, 16), 256, 0, stream>>>(W0, w0h, w0l, KDIM0, KT0);
  wconv_frag_kernel<<<dim3(16, 16), 256, 0, stream>>>(W1, w1h, w1l, HDIM, KTH);
  wconv_frag_kernel<<<dim3(16, 16), 256, 0, stream>>>(W2, w2h, w2l, HDIM, KTH);
  pack_wcat_kernel<<<384, 256, 0, stream>>>(Wp, Wv, wc);
  adecomp_frag_kernel<<<dim3(KP0 / 256, BATCH / 16), 256, 0, stream>>>(obs, obsh, obsl);

  // layer 0
  hipMemsetAsync(xf, 0, xbytes, stream);
  gemm_frag_kernel<<<dim3(8, 32, 2), 512, 0, stream>>>(obsh, obsl, w0h, w0l, xf, KT0, KT0 / 2);
  ln_relu_f16_frag_kernel<<<BATCH / 16, 1024, 0, stream>>>(xf, b0, g0, be0, xph, xpl);

  // layer 1
  hipMemsetAsync(xf, 0, xbytes, stream);
  gemm_frag_kernel<<<dim3(8, 32, 2), 512, 0, stream>>>(xph, xpl, w1h, w1l, xf, KTH, KTH / 2);
  ln_relu_f16_frag_kernel<<<BATCH / 16, 1024, 0, stream>>>(xf, b1, g1, be1, xph, xpl);

  // layer 2
  hipMemsetAsync(xf, 0, xbytes, stream);
  gemm_frag_kernel<<<dim3(8, 32, 2), 512, 0, stream>>>(xph, xpl, w2h, w2l, xf, KTH, KTH / 2);
  ln_relu_kernel<<<BATCH, 256, 0, stream>>>(xf, b2, g2, be2);

  // heads + sampling
  head_kernel<<<BATCH / 8, 256, 0, stream>>>(xf, wc, bp, bv, out);
  sample_kernel<<<BATCH, 64, 0, stream>>>(amask, gum, out);
}

// Round 5
// 586.163 us; speedup vs baseline: 1.5467x; 1.1709x over previous
//
#include <hip/hip_runtime.h>
#include <math.h>

#define BATCH 4096
#define HDIM  1024
#define KDIM0 7150
#define KP0   7168
#define KT0   224          // KP0/32
#define KTH   32           // HDIM/32
#define NACT  47
#define NA2   94
#define NEGC  -1000000000.0f

// output layout (floats): logits [0,385024), logp [385024,393216),
// actions [393216,401408), value [401408,405504)
#define LP_OFF  385024
#define ACT_OFF 393216
#define VAL_OFF 401408

typedef _Float16 half8_t  __attribute__((ext_vector_type(8)));
typedef _Float16 half4_t  __attribute__((ext_vector_type(4)));
typedef float    float4_t __attribute__((ext_vector_type(4)));

#define GLOAD16(gp, lp) __builtin_amdgcn_global_load_lds( \
    (__attribute__((address_space(1))) void*)(gp), \
    (__attribute__((address_space(3))) void*)(lp), 16, 0, 0)

// Fragment-tile order for a [R][Kp] f16 plane (R = rows of A / cols of W^T):
//   tile = rt*KT + kt ; within tile: lane = quad*16 + (r%16), quad=(k%32)/8,
//   halfs addr = tile*512 + lane*8 + (k%8).  (mfma_f32_16x16x32_f16 layout)

// ---------------------------------------------------------------------------
// Weight convert: W[K][HDIM] fp32 -> hi/lo f16 planes of W^T in fragment order.
// ---------------------------------------------------------------------------
__global__ __launch_bounds__(256) void wconv_frag_kernel(
    const float* __restrict__ W, _Float16* __restrict__ Wh,
    _Float16* __restrict__ Wl, int K, int KT)
{
  __shared__ float T[64][65];
  const int k0 = blockIdx.x * 64, n0 = blockIdx.y * 64, t = threadIdx.x;
#pragma unroll
  for (int p = 0; p < 16; ++p) {
    const int idx = p * 256 + t;
    const int r = idx >> 6, c = idx & 63;
    T[r][c] = (k0 + r < K) ? W[(size_t)(k0 + r) * HDIM + n0 + c] : 0.f;
  }
  __syncthreads();
#pragma unroll
  for (int ss = 0; ss < 2; ++ss) {
    const int s    = ss * 256 + t;
    const int tile = s >> 6;            // 0..7 = 2 kt x 4 nt
    const int ktl  = tile >> 2, ntl = tile & 3;
    const int lane = s & 63;
    const int quad = lane >> 4, nr = lane & 15;
    half8_t h, l;
#pragma unroll
    for (int j = 0; j < 8; ++j) {
      const float v = T[ktl * 32 + quad * 8 + j][ntl * 16 + nr];
      const _Float16 hh = (_Float16)v;
      h[j] = hh;
      l[j] = (_Float16)((v - (float)hh) * 4096.f);
    }
    const size_t o = ((size_t)((n0 / 16 + ntl) * KT + (k0 / 32 + ktl)) * 64 + lane) * 8;
    *(half8_t*)(Wh + o) = h;
    *(half8_t*)(Wl + o) = l;
  }
}

// ---------------------------------------------------------------------------
// obs decompose: obs[4096][7150] fp32 -> hi/lo planes frag order (K padded).
// ---------------------------------------------------------------------------
__global__ __launch_bounds__(256) void adecomp_frag_kernel(
    const float* __restrict__ A, _Float16* __restrict__ Ah,
    _Float16* __restrict__ Al)
{
  __shared__ float Xs[16][257];
  const int t  = threadIdx.x;
  const int mt = blockIdx.y;
  const int kb = blockIdx.x * 256;
  const int lr = t >> 4;
  const int lk = (t & 15) * 16;
  const float* src = A + (size_t)(mt * 16 + lr) * KDIM0 + kb + lk;
#pragma unroll
  for (int c = 0; c < 4; ++c) {
    const int kg = kb + lk + c * 4;
    float4 vv = make_float4(0.f, 0.f, 0.f, 0.f);
    if (kg + 3 < KDIM0) {
      vv = *(const float4*)(src + c * 4);
    } else {
      if (kg     < KDIM0) vv.x = src[c * 4];
      if (kg + 1 < KDIM0) vv.y = src[c * 4 + 1];
      if (kg + 2 < KDIM0) vv.z = src[c * 4 + 2];
      if (kg + 3 < KDIM0) vv.w = src[c * 4 + 3];
    }
    *(float4*)&Xs[lr][lk + c * 4] = vv;
  }
  __syncthreads();
#pragma unroll
  for (int ss = 0; ss < 2; ++ss) {
    const int s    = ss * 256 + t;
    const int ktl  = s >> 6;
    const int lane = s & 63;
    const int quad = lane >> 4, mr = lane & 15;
    half8_t h, l;
#pragma unroll
    for (int j = 0; j < 8; ++j) {
      const float v = Xs[mr][ktl * 32 + quad * 8 + j];
      const _Float16 hh = (_Float16)v;
      h[j] = hh;
      l[j] = (_Float16)((v - (float)hh) * 4096.f);
    }
    const size_t o = ((size_t)(mt * KT0 + blockIdx.x * 8 + ktl) * 64 + lane) * 8;
    *(half8_t*)(Ah + o) = h;
    *(half8_t*)(Al + o) = l;
  }
}

// ---------------------------------------------------------------------------
// f16x3 split GEMM, 16x16x32 MFMA, fragment-order planes, global_load_lds
// staging, BK=64 (2 k-tiles per barrier pair). Block 128x128, 512 thr =
// 8 waves (2m x 4n), wave tile 64x32. Split-K: kz z-block writes its own
// output buffer C + z*M*N (no atomics, no memset; consumer sums halves).
// ---------------------------------------------------------------------------
__global__ __launch_bounds__(512, 4) void gemm_frag2_kernel(
    const _Float16* __restrict__ Ah, const _Float16* __restrict__ Al,
    const _Float16* __restrict__ Wh, const _Float16* __restrict__ Wl,
    float* __restrict__ C, int KT, int ktsplit)
{
  __shared__ _Float16 As[2][2][8][512];   // [kt2][plane][mt][frag]
  __shared__ _Float16 Ws[2][2][8][512];
  const int t    = threadIdx.x;
  const int lane = t & 63;
  const int w    = t >> 6;
  const int nt0  = blockIdx.x * 8;
  const int mt0  = blockIdx.y * 8;
  const int ktb  = blockIdx.z * ktsplit;
  const int nit  = ktsplit >> 1;
  const int l15  = lane & 15, quad = lane >> 4;
  const int wmi  = (w >> 2) * 4;
  const int wni  = (w & 3) * 2;

  // wave w stages A m-tile mt0+w and W n-tile nt0+w (both planes, both kts)
  const _Float16* aS[2] = {
    Ah + (size_t)(mt0 + w) * KT * 512 + lane * 8,
    Al + (size_t)(mt0 + w) * KT * 512 + lane * 8 };
  const _Float16* wS[2] = {
    Wh + (size_t)(nt0 + w) * KT * 512 + lane * 8,
    Wl + (size_t)(nt0 + w) * KT * 512 + lane * 8 };

  float4_t acc[4][2], accx[4][2];
#pragma unroll
  for (int i = 0; i < 4; ++i)
#pragma unroll
    for (int j = 0; j < 2; ++j) {
      acc[i][j]  = (float4_t){0.f, 0.f, 0.f, 0.f};
      accx[i][j] = (float4_t){0.f, 0.f, 0.f, 0.f};
    }

  for (int it = 0; it < nit; ++it) {
    const size_t kb = (size_t)(ktb + it * 2) * 512;
#pragma unroll
    for (int k2 = 0; k2 < 2; ++k2)
#pragma unroll
      for (int pl = 0; pl < 2; ++pl) {
        GLOAD16(aS[pl] + kb + k2 * 512, &As[k2][pl][w][0]);
        GLOAD16(wS[pl] + kb + k2 * 512, &Ws[k2][pl][w][0]);
      }
    __syncthreads();
#pragma unroll
    for (int k2 = 0; k2 < 2; ++k2) {
      half8_t ah[4], al[4], wh[2], wl[2];
#pragma unroll
      for (int i = 0; i < 4; ++i) {
        ah[i] = *(const half8_t*)&As[k2][0][wmi + i][lane * 8];
        al[i] = *(const half8_t*)&As[k2][1][wmi + i][lane * 8];
      }
#pragma unroll
      for (int j = 0; j < 2; ++j) {
        wh[j] = *(const half8_t*)&Ws[k2][0][wni + j][lane * 8];
        wl[j] = *(const half8_t*)&Ws[k2][1][wni + j][lane * 8];
      }
#pragma unroll
      for (int i = 0; i < 4; ++i)
#pragma unroll
        for (int j = 0; j < 2; ++j) {
          acc[i][j]  = __builtin_amdgcn_mfma_f32_16x16x32_f16(ah[i], wh[j], acc[i][j], 0, 0, 0);
          accx[i][j] = __builtin_amdgcn_mfma_f32_16x16x32_f16(ah[i], wl[j], accx[i][j], 0, 0, 0);
          accx[i][j] = __builtin_amdgcn_mfma_f32_16x16x32_f16(al[i], wh[j], accx[i][j], 0, 0, 0);
        }
    }
    __syncthreads();
  }

  float* Cb = C + (size_t)blockIdx.z * ((size_t)BATCH * HDIM);
  const float sc = 1.0f / 4096.0f;
#pragma unroll
  for (int i = 0; i < 4; ++i) {
    const int row0 = (mt0 + wmi + i) * 16 + quad * 4;
#pragma unroll
    for (int j = 0; j < 2; ++j) {
      const int col = (nt0 + wni + j) * 16 + l15;
      float* cp = Cb + (size_t)row0 * HDIM + col;
#pragma unroll
      for (int r = 0; r < 4; ++r)
        cp[(size_t)r * HDIM] = acc[i][j][r] + accx[i][j][r] * sc;
    }
  }
}

// ---------------------------------------------------------------------------
// sum halves + bias + LayerNorm + ReLU -> hi/lo f16 planes (fragment order).
// 1024 thr = 16 waves; wave w = row mt*16+w, wave-local reductions.
// ---------------------------------------------------------------------------
__global__ __launch_bounds__(1024) void ln_relu_f16_frag_kernel(
    const float* __restrict__ x0, const float* __restrict__ x1,
    const float* __restrict__ bias,
    const float* __restrict__ g, const float* __restrict__ be,
    _Float16* __restrict__ oh, _Float16* __restrict__ ol)
{
  const int t = threadIdx.x;
  const int w = t >> 6, lane = t & 63;
  const int mt = blockIdx.x;
  const float* xr0 = x0 + (size_t)(mt * 16 + w) * HDIM;
  const float* xr1 = x1 + (size_t)(mt * 16 + w) * HDIM;

  float4 v[4];
  float s = 0.f;
#pragma unroll
  for (int c = 0; c < 4; ++c) {
    const int k = c * 256 + lane * 4;
    const float4 a = *(const float4*)(xr0 + k);
    const float4 b = *(const float4*)(xr1 + k);
    const float4 bb = *(const float4*)(bias + k);
    v[c].x = a.x + b.x + bb.x; v[c].y = a.y + b.y + bb.y;
    v[c].z = a.z + b.z + bb.z; v[c].w = a.w + b.w + bb.w;
    s += (v[c].x + v[c].y) + (v[c].z + v[c].w);
  }
#pragma unroll
  for (int o = 32; o; o >>= 1) s += __shfl_xor(s, o, 64);
  const float mean = s * (1.0f / HDIM);

  float s2 = 0.f;
#pragma unroll
  for (int c = 0; c < 4; ++c) {
    v[c].x -= mean; v[c].y -= mean; v[c].z -= mean; v[c].w -= mean;
    s2 += (v[c].x * v[c].x + v[c].y * v[c].y) + (v[c].z * v[c].z + v[c].w * v[c].w);
  }
#pragma unroll
  for (int o = 32; o; o >>= 1) s2 += __shfl_xor(s2, o, 64);
  const float inv = 1.0f / sqrtf(s2 * (1.0f / HDIM) + 1e-5f);

  const int kt_b  = lane >> 3;
  const int quad  = (lane >> 1) & 3;
  const int jb    = (lane & 1) * 4;
#pragma unroll
  for (int c = 0; c < 4; ++c) {
    const int k = c * 256 + lane * 4;
    const float4 gg = *(const float4*)(g + k);
    const float4 ee = *(const float4*)(be + k);
    float r0 = fmaxf(fmaf(v[c].x * inv, gg.x, ee.x), 0.f);
    float r1 = fmaxf(fmaf(v[c].y * inv, gg.y, ee.y), 0.f);
    float r2 = fmaxf(fmaf(v[c].z * inv, gg.z, ee.z), 0.f);
    float r3 = fmaxf(fmaf(v[c].w * inv, gg.w, ee.w), 0.f);
    const _Float16 h0 = (_Float16)r0, h1 = (_Float16)r1, h2 = (_Float16)r2, h3 = (_Float16)r3;
    const half4_t hv = {h0, h1, h2, h3};
    const half4_t lv = {(_Float16)((r0 - (float)h0) * 4096.f),
                        (_Float16)((r1 - (float)h1) * 4096.f),
                        (_Float16)((r2 - (float)h2) * 4096.f),
                        (_Float16)((r3 - (float)h3) * 4096.f)};
    const int kt = c * 8 + kt_b;
    const size_t o = ((size_t)(mt * KTH + kt) * 64 + quad * 16 + w) * 8 + jb;
    *(half4_t*)(oh + o) = hv;
    *(half4_t*)(ol + o) = lv;
  }
}

// ---------------------------------------------------------------------------
// Pack Wcat[1024][96]: cols 0..93 = Wp, col 94 = Wv, col 95 = 0
// ---------------------------------------------------------------------------
__global__ __launch_bounds__(256) void pack_wcat_kernel(
    const float* __restrict__ Wp, const float* __restrict__ Wv,
    float* __restrict__ Wc)
{
  const int i = blockIdx.x * 256 + threadIdx.x;
  const int k = i / 96, c = i % 96;
  float v = 0.f;
  if (c < 94)       v = Wp[(size_t)k * 94 + c];
  else if (c == 94) v = Wv[k];
  Wc[i] = v;
}

// ---------------------------------------------------------------------------
// Fused: sum halves + bias + LN + ReLU  ->  head GEMM (+bp/bv)  ->  gumbel
// sampling. Block = 8 batch rows, 256 thr (4 waves).
// ---------------------------------------------------------------------------
__global__ __launch_bounds__(256) void head_fused_kernel(
    const float* __restrict__ x0, const float* __restrict__ x1,
    const float* __restrict__ b2, const float* __restrict__ g2,
    const float* __restrict__ be2,
    const float* __restrict__ Wc, const float* __restrict__ bp,
    const float* __restrict__ bv,
    const int* __restrict__ amask, const float* __restrict__ gum,
    float* __restrict__ out)
{
  __shared__ float Xs[8][1025];
  __shared__ float red[4][8][96];
  __shared__ float fl[8][96];
  __shared__ float rstat[16];
  const int t  = threadIdx.x;
  const int r0 = blockIdx.x * 8;
  const int wv = t >> 6, lane = t & 63;

  // stage: sum halves + pre-LN bias
#pragma unroll 4
  for (int i = 0; i < 32; ++i) {
    const int e = i * 256 + t;
    const int r = e >> 10, k = e & 1023;
    const size_t gi = (size_t)(r0 + r) * HDIM + k;
    Xs[r][k] = x0[gi] + x1[gi] + b2[k];
  }
  __syncthreads();

  // LN stats: wave wv handles rows wv and wv+4 (two-pass, matches reference)
#pragma unroll
  for (int rr = 0; rr < 2; ++rr) {
    const int row = wv + rr * 4;
    float s = 0.f;
#pragma unroll
    for (int ii = 0; ii < 16; ++ii) s += Xs[row][lane + 64 * ii];
#pragma unroll
    for (int o = 32; o; o >>= 1) s += __shfl_xor(s, o, 64);
    const float mean = s * (1.0f / HDIM);
    float s2 = 0.f;
#pragma unroll
    for (int ii = 0; ii < 16; ++ii) {
      const float d = Xs[row][lane + 64 * ii] - mean;
      s2 += d * d;
    }
#pragma unroll
    for (int o = 32; o; o >>= 1) s2 += __shfl_xor(s2, o, 64);
    if (lane == 0) {
      rstat[row] = mean;
      rstat[8 + row] = 1.0f / sqrtf(s2 * (1.0f / HDIM) + 1e-5f);
    }
  }
  __syncthreads();

  // normalize + relu in place
#pragma unroll 4
  for (int i = 0; i < 32; ++i) {
    const int e = i * 256 + t;
    const int r = e >> 10, k = e & 1023;
    Xs[r][k] = fmaxf(fmaf((Xs[r][k] - rstat[r]) * rstat[8 + r], g2[k], be2[k]), 0.f);
  }
  __syncthreads();

  // head GEMM: 16 tx (6 cols) x 4 ty (2 rows) x 4 kz
  const int tx = t & 15;
  const int ty = (t >> 4) & 3;
  const int kz = t >> 6;
  const int c0 = tx * 6;
  float acc[2][6] = {{0.f,0.f,0.f,0.f,0.f,0.f},{0.f,0.f,0.f,0.f,0.f,0.f}};
  const int kkend = kz * 256 + 256;
  for (int kk = kz * 256; kk < kkend; ++kk) {
    const float xa = Xs[ty * 2][kk];
    const float xb = Xs[ty * 2 + 1][kk];
    const float* wrow = Wc + (size_t)kk * 96 + c0;
    const float2 w01 = *(const float2*)(wrow);
    const float2 w23 = *(const float2*)(wrow + 2);
    const float2 w45 = *(const float2*)(wrow + 4);
    const float wvv[6] = {w01.x, w01.y, w23.x, w23.y, w45.x, w45.y};
#pragma unroll
    for (int j = 0; j < 6; ++j) {
      acc[0][j] = fmaf(xa, wvv[j], acc[0][j]);
      acc[1][j] = fmaf(xb, wvv[j], acc[1][j]);
    }
  }
#pragma unroll
  for (int r = 0; r < 2; ++r)
#pragma unroll
    for (int j = 0; j < 6; ++j) red[kz][ty * 2 + r][c0 + j] = acc[r][j];
  __syncthreads();

#pragma unroll
  for (int q = 0; q < 3; ++q) {
    const int e = t * 3 + q;
    const int row = e / 96, c = e % 96;
    const float sum = red[0][row][c] + red[1][row][c] + red[2][row][c] + red[3][row][c];
    if (c < 94) {
      const float vv = sum + bp[c];
      out[(size_t)(r0 + row) * NA2 + c] = vv;
      fl[row][c] = vv;
    } else if (c == 94) {
      out[VAL_OFF + r0 + row] = sum + bv[0];
    }
  }
  __syncthreads();

  // sampling: wave wv handles batch rows wv and wv+4
#pragma unroll
  for (int rr = 0; rr < 2; ++rr) {
    const int row = wv + rr * 4;
    const int b = r0 + row;
    const bool valid = lane < NACT;

    const float lg1 = valid ? fl[row][lane] : 0.f;
    const float lg2 = valid ? fl[row][NACT + lane] : 0.f;
    const int   mk1 = valid ? amask[(size_t)b * NA2 + lane] : 0;
    const int   mk2 = valid ? amask[(size_t)b * NA2 + NACT + lane] : 0;
    const float gu1 = valid ? gum[(size_t)b * NA2 + lane] : 0.f;
    const float gu2 = valid ? gum[(size_t)b * NA2 + NACT + lane] : 0.f;

    const float l1 = valid ? ((mk1 == 0) ? NEGC : lg1) : -INFINITY;
    float key = valid ? (l1 + gu1) : -INFINITY;
    int idx = lane;
#pragma unroll
    for (int o = 32; o; o >>= 1) {
      const float ok = __shfl_xor(key, o, 64);
      const int   oi = __shfl_xor(idx, o, 64);
      if (ok > key || (ok == key && oi < idx)) { key = ok; idx = oi; }
    }
    const int a1 = idx;

    float mx = l1;
#pragma unroll
    for (int o = 32; o; o >>= 1) mx = fmaxf(mx, __shfl_xor(mx, o, 64));
    float ex = valid ? expf(l1 - mx) : 0.f;
#pragma unroll
    for (int o = 32; o; o >>= 1) ex += __shfl_xor(ex, o, 64);
    const float logp1 = __shfl(l1, a1, 64) - (mx + logf(ex));

    int m2 = mk2;
    if (a1 >= 1 && a1 <= 6 && lane == a1) m2 = 0;
    if (a1 > 26 && a1 <= 46 && lane >= 27 && valid) m2 = 0;
    if (a1 == 0 && lane == 0) m2 = 0;
    int tot = m2;
#pragma unroll
    for (int o = 32; o; o >>= 1) tot += __shfl_xor(tot, o, 64);
    if (a1 == 0 && tot == 0 && lane == 0) m2 = 1;

    const float l2 = valid ? ((m2 == 0) ? NEGC : lg2) : -INFINITY;
    float key2 = valid ? (l2 + gu2) : -INFINITY;
    int idx2 = lane;
#pragma unroll
    for (int o = 32; o; o >>= 1) {
      const float ok = __shfl_xor(key2, o, 64);
      const int   oi = __shfl_xor(idx2, o, 64);
      if (ok > key2 || (ok == key2 && oi < idx2)) { key2 = ok; idx2 = oi; }
    }
    const int a2 = idx2;

    float mx2 = l2;
#pragma unroll
    for (int o = 32; o; o >>= 1) mx2 = fmaxf(mx2, __shfl_xor(mx2, o, 64));
    float ex2 = valid ? expf(l2 - mx2) : 0.f;
#pragma unroll
    for (int o = 32; o; o >>= 1) ex2 += __shfl_xor(ex2, o, 64);
    const float logp2 = __shfl(l2, a2, 64) - (mx2 + logf(ex2));

    if (lane == 0) {
      out[LP_OFF  + b * 2]     = logp1;
      out[LP_OFF  + b * 2 + 1] = logp2;
      out[ACT_OFF + b * 2]     = (float)a1;
      out[ACT_OFF + b * 2 + 1] = (float)a2;
    }
  }
}

// ---------------------------------------------------------------------------
extern "C" void kernel_launch(void* const* d_in, const int* in_sizes, int n_in,
                              void* d_out, int out_size, void* d_ws, size_t ws_size,
                              hipStream_t stream) {
  (void)in_sizes; (void)n_in; (void)out_size; (void)ws_size;
  const float* obs   = (const float*)d_in[0];
  const int*   amask = (const int*)  d_in[1];
  const float* gum   = (const float*)d_in[2];
  const float* W0    = (const float*)d_in[3];
  const float* b0    = (const float*)d_in[4];
  const float* g0    = (const float*)d_in[5];
  const float* be0   = (const float*)d_in[6];
  const float* W1    = (const float*)d_in[7];
  const float* b1    = (const float*)d_in[8];
  const float* g1    = (const float*)d_in[9];
  const float* be1   = (const float*)d_in[10];
  const float* W2    = (const float*)d_in[11];
  const float* b2    = (const float*)d_in[12];
  const float* g2    = (const float*)d_in[13];
  const float* be2   = (const float*)d_in[14];
  const float* Wp    = (const float*)d_in[15];
  const float* bp    = (const float*)d_in[16];
  const float* Wv    = (const float*)d_in[17];
  const float* bv    = (const float*)d_in[18];
  float* out = (float*)d_out;

  char* ws = (char*)d_ws;
  size_t off = 0;
  auto take = [&](size_t n) { char* p = ws + off; off += (n + 255) & ~(size_t)255; return p; };
  _Float16* obsh = (_Float16*)take((size_t)BATCH * KP0 * 2);   // 58.7 MB
  _Float16* obsl = (_Float16*)take((size_t)BATCH * KP0 * 2);   // 58.7 MB
  _Float16* w0h  = (_Float16*)take((size_t)HDIM * KP0 * 2);    // 14.7 MB
  _Float16* w0l  = (_Float16*)take((size_t)HDIM * KP0 * 2);    // 14.7 MB
  _Float16* w1h  = (_Float16*)take((size_t)HDIM * HDIM * 2);
  _Float16* w1l  = (_Float16*)take((size_t)HDIM * HDIM * 2);
  _Float16* w2h  = (_Float16*)take((size_t)HDIM * HDIM * 2);
  _Float16* w2l  = (_Float16*)take((size_t)HDIM * HDIM * 2);
  float*    xf   = (float*)   take((size_t)2 * BATCH * HDIM * 4); // 33.6 MB (2 halves)
  float*    wc   = (float*)   take((size_t)HDIM * 96 * 4);
  // activation f16 planes alias the (dead after GEMM0) W0 plane region
  _Float16* xph  = w0h;
  _Float16* xpl  = w0l;
  float* xf1 = xf + (size_t)BATCH * HDIM;

  // conversions into fragment order
  wconv_frag_kernel<<<dim3(KP0 / 64, 16), 256, 0, stream>>>(W0, w0h, w0l, KDIM0, KT0);
  wconv_frag_kernel<<<dim3(16, 16), 256, 0, stream>>>(W1, w1h, w1l, HDIM, KTH);
  wconv_frag_kernel<<<dim3(16, 16), 256, 0, stream>>>(W2, w2h, w2l, HDIM, KTH);
  pack_wcat_kernel<<<384, 256, 0, stream>>>(Wp, Wv, wc);
  adecomp_frag_kernel<<<dim3(KP0 / 256, BATCH / 16), 256, 0, stream>>>(obs, obsh, obsl);

  // layer 0
  gemm_frag2_kernel<<<dim3(8, 32, 2), 512, 0, stream>>>(obsh, obsl, w0h, w0l, xf, KT0, KT0 / 2);
  ln_relu_f16_frag_kernel<<<BATCH / 16, 1024, 0, stream>>>(xf, xf1, b0, g0, be0, xph, xpl);

  // layer 1
  gemm_frag2_kernel<<<dim3(8, 32, 2), 512, 0, stream>>>(xph, xpl, w1h, w1l, xf, KTH, KTH / 2);
  ln_relu_f16_frag_kernel<<<BATCH / 16, 1024, 0, stream>>>(xf, xf1, b1, g1, be1, xph, xpl);

  // layer 2
  gemm_frag2_kernel<<<dim3(8, 32, 2), 512, 0, stream>>>(xph, xpl, w2h, w2l, xf, KTH, KTH / 2);

  // fused final-LN + heads + sampling
  head_fused_kernel<<<BATCH / 8, 256, 0, stream>>>(
      xf, xf1, b2, g2, be2, wc, bp, bv, amask, gum, out);
}